// Round 8
// baseline (391.831 us; speedup 1.0000x reference)
//
#include <hip/hip_runtime.h>
#include <math.h>

typedef __bf16 bf16_t;
typedef __bf16 bf16x8 __attribute__((ext_vector_type(8)));
typedef float f32x4 __attribute__((ext_vector_type(4)));

#define B_    2
#define LQ    4096
#define LK    1024
#define QDIM  2048
#define KVDIM 2048
#define H_    16
#define HD_   128
#define KVC_  512
#define QC_   768
#define R_    64

// fused row widths
#define QCOMB 3072   // [q_nope(2048) | q_rope(1024)]
#define KCOMB 4224   // [k_nope(2048) | v(2048) | k_rope(64) | pad(64)]

typedef __attribute__((address_space(1))) void gvoid_t;
typedef __attribute__((address_space(3))) void lvoid_t;

static __device__ __forceinline__ void gld_lds16(const void* g, void* l) {
  __builtin_amdgcn_global_load_lds((gvoid_t*)(void*)g, (lvoid_t*)l, 16, 0, 0);
}

// ---------------- fused fp32 -> bf16 convert for q and kv (1 launch) ----------------
__global__ void cvt2_f32_bf16(const float* __restrict__ a, bf16_t* __restrict__ oa, long na,
                              const float* __restrict__ b, bf16_t* __restrict__ ob, long nb) {
  const long stride = (long)gridDim.x * blockDim.x * 8;
  for (long i = ((long)blockIdx.x * blockDim.x + threadIdx.x) * 8; i < na; i += stride) {
    float4 x = *(const float4*)(a + i);
    float4 y = *(const float4*)(a + i + 4);
    bf16x8 t;
    t[0] = (bf16_t)x.x; t[1] = (bf16_t)x.y; t[2] = (bf16_t)x.z; t[3] = (bf16_t)x.w;
    t[4] = (bf16_t)y.x; t[5] = (bf16_t)y.y; t[6] = (bf16_t)y.z; t[7] = (bf16_t)y.w;
    *(bf16x8*)(oa + i) = t;
  }
  for (long i = ((long)blockIdx.x * blockDim.x + threadIdx.x) * 8; i < nb; i += stride) {
    float4 x = *(const float4*)(b + i);
    float4 y = *(const float4*)(b + i + 4);
    bf16x8 t;
    t[0] = (bf16_t)x.x; t[1] = (bf16_t)x.y; t[2] = (bf16_t)x.z; t[3] = (bf16_t)x.w;
    t[4] = (bf16_t)y.x; t[5] = (bf16_t)y.y; t[6] = (bf16_t)y.z; t[7] = (bf16_t)y.w;
    *(bf16x8*)(ob + i) = t;
  }
}

// ---------------- fused transpose+convert for ALL weights (1 launch) ----------------
struct TransAll {
  const float* src[8];
  bf16_t* dst[8];
  int K[8], N[8], gx[8];
  int off[9];
};

__global__ __launch_bounds__(256) void transpose_all(TransAll d) {
  const int bid = blockIdx.x;
  int i = 0;
#pragma unroll
  for (int j = 1; j < 8; ++j) if (bid >= d.off[j]) i = j;
  const float* __restrict__ src = d.src[i];
  bf16_t* __restrict__ dst = d.dst[i];
  const int K = d.K[i], N = d.N[i];
  const int local = bid - d.off[i];
  const int gx = d.gx[i];
  const int bx = (local % gx) * 32, by = (local / gx) * 32;
  __shared__ float t[32][33];
  const int x = threadIdx.x, y = threadIdx.y;
#pragma unroll
  for (int j = 0; j < 32; j += 8)
    t[y + j][x] = src[(size_t)(by + y + j) * N + bx + x];
  __syncthreads();
#pragma unroll
  for (int j = 0; j < 32; j += 8)
    dst[(size_t)(bx + y + j) * K + by + x] = (bf16_t)t[x][y + j];
}

// ---------------- small-M bf16 MFMA GEMM (128x128, BK=64, 4 waves) ----------------
template <typename CT>
__global__ __launch_bounds__(256) void gemm_bt(
    const bf16_t* __restrict__ A, const bf16_t* __restrict__ Bt,
    CT* __restrict__ C, int M, int N, int K) {
  __shared__ __align__(16) bf16_t lA[128 * 64];
  __shared__ __align__(16) bf16_t lB[128 * 64];
  const int tid = threadIdx.x;
  const int wave = tid >> 6, lane = tid & 63;

  const int gx = gridDim.x, gy = gridDim.y;
  const int nwg = gx * gy;
  int bx, by;
  if (((nwg & 7) == 0) && ((gy & 7) == 0)) {
    const int orig = blockIdx.y * gx + blockIdx.x;
    const int wg = (orig & 7) * (nwg >> 3) + (orig >> 3);
    const int gxB = gx << 3;
    const int band = wg / gxB, rem = wg % gxB;
    bx = rem >> 3;
    by = (band << 3) + (rem & 7);
  } else {
    bx = blockIdx.x; by = blockIdx.y;
  }

  const int row0 = by * 128, col0 = bx * 128;
  const int wr = (wave >> 1) * 64, wc = (wave & 1) * 64;
  f32x4 acc[4][4] = {};
  const int kT = K >> 6;
  const int lr = lane >> 3;
  const int lc8 = (lane & 7) * 8;

  for (int kt = 0; kt < kT; ++kt) {
    const int k0 = kt << 6;
    __syncthreads();
#pragma unroll
    for (int j = 0; j < 4; ++j) {
      const int c = wave * 4 + j;
      const bf16_t* ga = A + (size_t)(row0 + c * 8 + lr) * K + k0 + lc8;
      gld_lds16(ga, &lA[c * 512]);
      const bf16_t* gb = Bt + (size_t)(col0 + c * 8 + lr) * K + k0 + lc8;
      gld_lds16(gb, &lB[c * 512]);
    }
    __syncthreads();
#pragma unroll
    for (int kk = 0; kk < 2; ++kk) {
      bf16x8 af[4], bfr[4];
      const int kc = kk * 32 + (lane >> 4) * 8;
      const int fr = lane & 15;
#pragma unroll
      for (int m = 0; m < 4; ++m)
        af[m] = *(const bf16x8*)&lA[(wr + m * 16 + fr) * 64 + kc];
#pragma unroll
      for (int n = 0; n < 4; ++n)
        bfr[n] = *(const bf16x8*)&lB[(wc + n * 16 + fr) * 64 + kc];
#pragma unroll
      for (int m = 0; m < 4; ++m)
#pragma unroll
        for (int n = 0; n < 4; ++n)
          acc[m][n] = __builtin_amdgcn_mfma_f32_16x16x32_bf16(af[m], bfr[n], acc[m][n], 0, 0, 0);
    }
  }
  const int fr = lane & 15, fq = lane >> 4;
#pragma unroll
  for (int m = 0; m < 4; ++m)
#pragma unroll
    for (int n = 0; n < 4; ++n) {
      const int col = col0 + wc + n * 16 + fr;
#pragma unroll
      for (int r = 0; r < 4; ++r) {
        const int row = row0 + wr + m * 16 + fq * 4 + r;
        C[(size_t)row * N + col] = (CT)acc[m][n][r];
      }
    }
}

// ---------------- big pipelined GEMM v2: BM=256, BN=TN, BK=64, 8 waves (2Mx4N) ----------------
template <int TN, typename CT>
__global__ __launch_bounds__(512, 2) void gemm_big2(
    const bf16_t* __restrict__ A, const bf16_t* __restrict__ Bt,
    CT* __restrict__ C, int M, int N, int K) {
  constexpr int NF = TN / 64;
  constexpr int LW = 4 + TN / 64;
  __shared__ __align__(16) bf16_t lA[2][256 * 64];
  __shared__ __align__(16) bf16_t lB[2][TN * 64];
  const int tid = threadIdx.x;
  const int w = tid >> 6, lane = tid & 63;

  const int gx = gridDim.x;
  const int nwg = gx * gridDim.y;
  const int orig = blockIdx.y * gx + blockIdx.x;
  const int wg = (orig & 7) * (nwg >> 3) + (orig >> 3);
  const int bx = wg % gx, by = wg / gx;

  const int row0 = by * 256, col0 = bx * TN;
  const int wm = w >> 2, wn = w & 3;
  const int lr = lane >> 3;
  const int kswz = ((lane & 7) ^ lr) * 8;
  const int nt = K >> 6;
  const int fr = lane & 15, fq = lane >> 4;

  auto STAGE = [&](int t, int buf) {
    const int k0 = t << 6;
#pragma unroll
    for (int j = 0; j < 4; ++j) {
      const int s = j * 8 + w;
      gld_lds16(A + (size_t)(row0 + s * 8 + lr) * K + k0 + kswz, &lA[buf][s * 512]);
    }
#pragma unroll
    for (int j = 0; j < TN / 64; ++j) {
      const int s = j * 8 + w;
      gld_lds16(Bt + (size_t)(col0 + s * 8 + lr) * K + k0 + kswz, &lB[buf][s * 512]);
    }
  };

  bf16x8 aA[8], bA[NF], aB[8], bB[NF];
  f32x4 acc[8][NF];
#pragma unroll
  for (int i = 0; i < 8; ++i)
#pragma unroll
    for (int j = 0; j < NF; ++j) acc[i][j] = f32x4{0.f, 0.f, 0.f, 0.f};

  auto READ = [&](int buf, int kk, bf16x8* a, bf16x8* b) {
    const int swzk = (kk * 32 + fq * 8) ^ ((fr & 7) << 3);
#pragma unroll
    for (int mf = 0; mf < 8; ++mf)
      a[mf] = *(const bf16x8*)&lA[buf][(wm * 128 + mf * 16 + fr) * 64 + swzk];
#pragma unroll
    for (int nf = 0; nf < NF; ++nf)
      b[nf] = *(const bf16x8*)&lB[buf][(wn * (TN / 4) + nf * 16 + fr) * 64 + swzk];
  };
  auto MF = [&](bf16x8* a, bf16x8* b) {
    __builtin_amdgcn_s_setprio(1);
#pragma unroll
    for (int mf = 0; mf < 8; ++mf)
#pragma unroll
      for (int nf = 0; nf < NF; ++nf)
        acc[mf][nf] = __builtin_amdgcn_mfma_f32_16x16x32_bf16(a[mf], b[nf], acc[mf][nf], 0, 0, 0);
    __builtin_amdgcn_s_setprio(0);
  };

  STAGE(0, 0);
  STAGE(1, 1);
  if constexpr (LW == 8) { asm volatile("s_waitcnt vmcnt(8)" ::: "memory"); }
  else                   { asm volatile("s_waitcnt vmcnt(6)" ::: "memory"); }
  __builtin_amdgcn_sched_barrier(0);
  __builtin_amdgcn_s_barrier();
  READ(0, 0, aA, bA);

  for (int t = 0; t < nt; ++t) {
    const int buf = t & 1;
    READ(buf, 1, aB, bB);
    __builtin_amdgcn_sched_barrier(0);
    MF(aA, bA);
    asm volatile("s_waitcnt lgkmcnt(0)" ::: "memory");
    __builtin_amdgcn_sched_barrier(0);
    __builtin_amdgcn_s_barrier();
    if (t + 2 < nt) {
      STAGE(t + 2, buf);
      if constexpr (LW == 8) { asm volatile("s_waitcnt vmcnt(8)" ::: "memory"); }
      else                   { asm volatile("s_waitcnt vmcnt(6)" ::: "memory"); }
    } else {
      asm volatile("s_waitcnt vmcnt(0)" ::: "memory");
    }
    __builtin_amdgcn_sched_barrier(0);
    __builtin_amdgcn_s_barrier();
    if (t + 1 < nt) READ(buf ^ 1, 0, aA, bA);
    __builtin_amdgcn_sched_barrier(0);
    MF(aB, bB);
  }

#pragma unroll
  for (int mf = 0; mf < 8; ++mf)
#pragma unroll
    for (int nf = 0; nf < NF; ++nf) {
      const int col = col0 + wn * (TN / 4) + nf * 16 + fr;
#pragma unroll
      for (int r = 0; r < 4; ++r) {
        const int row = row0 + wm * 128 + mf * 16 + fq * 4 + r;
        C[(size_t)row * N + col] = (CT)acc[mf][nf][r];
      }
    }
}

// ---------------- 8-phase GEMM v3: one-phase register lookahead ----------------
// BM=BN=256, BK=64, 8 waves (2Mx4N). LDS 128 KiB = 2 buf x 2 half x 128x64 x (A,B).
// Every MFMA cluster consumes operands read >=1 full cluster earlier (in regs);
// reads issued in a phase drain UNDER the cluster (compiler counted lgkmcnt; no
// lgkmcnt(0) asm). Read schedule (per wave): ph0: B1(t)[4] -> used ph1;
// ph1: A1(t)[8] -> ph2; ph2 (after vmcnt(6)+HBAR): B0(t+1)[4] -> ph0(t+1);
// ph3 (after vmcnt(4)+HBAR): A0(t+1)[8] -> ph0(t+1). MFMA: ph0 (A0,B0),
// ph1 (A0,B1), ph2 (A1,B1), ph3 (A1,B0-held).
// Stage schedule: ph0 A0(t+1)->buf^1, ph1 A1(t+1)->buf^1, ph2 B0(t+2)->buf,
// ph3 B1(t+2)->buf. vmcnt ledger: ph3(t-1) vmcnt(4) leaves {B0(t+1),B1(t+1)};
// ph2(t) after +6 loads vmcnt(6) -> B halves of t+1 landed; ph3(t) vmcnt(4)
// -> all of t+1 landed. Overwrite audit: each staged region's prior reads were
// consumed by an MFMA >=2 hard barriers earlier. B0 regs double-buffered by
// tile parity (loop unrolled x2; nt must be even; all reg indices static).
#define SWZK_(ks) (((ks) * 32 + fq * 8) ^ ((fr & 7) << 3))
#define RDA(buf, q, dst) { _Pragma("unroll") for (int mf = 0; mf < 4; ++mf) { \
    dst[mf][0] = *(const bf16x8*)&lA[buf][wm][((q) * 64 + mf * 16 + fr) * 64 + SWZK_(0)]; \
    dst[mf][1] = *(const bf16x8*)&lA[buf][wm][((q) * 64 + mf * 16 + fr) * 64 + SWZK_(1)]; } }
#define RDB(buf, nq, dst) { _Pragma("unroll") for (int nf = 0; nf < 2; ++nf) { \
    dst[nf][0] = *(const bf16x8*)&lB[buf][wbh][(wbr + (nq) * 32 + nf * 16 + fr) * 64 + SWZK_(0)]; \
    dst[nf][1] = *(const bf16x8*)&lB[buf][wbh][(wbr + (nq) * 32 + nf * 16 + fr) * 64 + SWZK_(1)]; } }
#define MFQ(a, b, mq, nq) { __builtin_amdgcn_s_setprio(1); \
  _Pragma("unroll") for (int mf = 0; mf < 4; ++mf) \
  _Pragma("unroll") for (int nf = 0; nf < 2; ++nf) { \
    acc[(mq)*4+mf][(nq)*2+nf] = __builtin_amdgcn_mfma_f32_16x16x32_bf16(a[mf][0], b[nf][0], acc[(mq)*4+mf][(nq)*2+nf], 0, 0, 0); \
    acc[(mq)*4+mf][(nq)*2+nf] = __builtin_amdgcn_mfma_f32_16x16x32_bf16(a[mf][1], b[nf][1], acc[(mq)*4+mf][(nq)*2+nf], 0, 0, 0); } \
  __builtin_amdgcn_s_setprio(0); }
#define SBAR_ __builtin_amdgcn_sched_barrier(0)
#define HBAR_ __builtin_amdgcn_s_barrier()

#define TILE8(t, B0C, B0N) { \
  const int buf = (t) & 1; \
  /* ph0: MFMA(A0,B0); read B1(t); stage A0(t+1) */ \
  if ((t) + 1 < nt) stA((t) + 1, 0, buf ^ 1); \
  RDB(buf, 1, br1); \
  SBAR_; MFQ(arC, B0C, 0, 0); SBAR_; HBAR_; \
  /* ph1: MFMA(A0,B1); read A1(t); stage A1(t+1) */ \
  if ((t) + 1 < nt) stA((t) + 1, 1, buf ^ 1); \
  RDA(buf, 1, arN); \
  SBAR_; MFQ(arC, br1, 0, 1); SBAR_; HBAR_; \
  /* ph2: stage B0(t+2); vmcnt(6) -> B halves of t+1 landed; read B0(t+1); MFMA(A1,B1) */ \
  if ((t) + 2 < nt) stB((t) + 2, 0, buf); \
  if ((t) + 1 < nt) { \
    asm volatile("s_waitcnt vmcnt(6)" ::: "memory"); \
    SBAR_; HBAR_; SBAR_; \
    RDB(buf ^ 1, 0, B0N); \
  } \
  SBAR_; MFQ(arN, br1, 1, 1); SBAR_; HBAR_; \
  /* ph3: stage B1(t+2); vmcnt(4) -> all of t+1 landed; read A0(t+1); MFMA(A1,B0) */ \
  if ((t) + 2 < nt) { stB((t) + 2, 1, buf); asm volatile("s_waitcnt vmcnt(4)" ::: "memory"); } \
  else { asm volatile("s_waitcnt vmcnt(0)" ::: "memory"); } \
  SBAR_; HBAR_; SBAR_; \
  if ((t) + 1 < nt) RDA(buf ^ 1, 0, arC); \
  SBAR_; MFQ(arN, B0C, 1, 0); SBAR_; HBAR_; \
}

template <typename CT>
__global__ __launch_bounds__(512, 2) void gemm_8ph(
    const bf16_t* __restrict__ A, const bf16_t* __restrict__ Bt,
    CT* __restrict__ C, int M, int N, int K) {
  __shared__ __align__(16) bf16_t lA[2][2][128 * 64];
  __shared__ __align__(16) bf16_t lB[2][2][128 * 64];
  const int tid = threadIdx.x;
  const int w = tid >> 6, lane = tid & 63;

  const int gx = gridDim.x;
  const int nwg = gx * gridDim.y;
  const int orig = blockIdx.y * gx + blockIdx.x;
  const int wg = (orig & 7) * (nwg >> 3) + (orig >> 3);
  const int bx = wg % gx, by = wg / gx;

  const int row0 = by * 256, col0 = bx * 256;
  const int wm = w >> 2, wn = w & 3;          // 2M x 4N waves, wave tile 128x64
  const int lr = lane >> 3;
  const int kswz = ((lane & 7) ^ lr) * 8;     // pre-swizzled global k-offset
  const int nt = K >> 6;                      // must be even
  const int fr = lane & 15, fq = lane >> 4;
  const int wbh = wn >> 1;                    // B LDS half this wave reads
  const int wbr = (wn & 1) * 64;              // row base within that half

  auto stA = [&](int t, int h, int buf) {     // stage A half-tile (128 rows x 64 k)
    const bf16_t* g = A + (size_t)(row0 + h * 128 + w * 8 + lr) * K + (t << 6) + kswz;
    gld_lds16(g, &lA[buf][h][w * 8 * 64]);
    gld_lds16(g + (size_t)64 * K, &lA[buf][h][(64 + w * 8) * 64]);
  };
  auto stB = [&](int t, int h, int buf) {
    const bf16_t* g = Bt + (size_t)(col0 + h * 128 + w * 8 + lr) * K + (t << 6) + kswz;
    gld_lds16(g, &lB[buf][h][w * 8 * 64]);
    gld_lds16(g + (size_t)64 * K, &lB[buf][h][(64 + w * 8) * 64]);
  };

  bf16x8 arC[4][2], arN[4][2], br1[2][2], brE[2][2], brO[2][2];
  f32x4 acc[8][4];
#pragma unroll
  for (int i = 0; i < 8; ++i)
#pragma unroll
    for (int j = 0; j < 4; ++j) acc[i][j] = f32x4{0.f, 0.f, 0.f, 0.f};

  // prologue: tile0 all 4 halves + tile1 B halves; wait tile0; read A0(0),B0(0)
  stA(0, 0, 0); stA(0, 1, 0); stB(0, 0, 0); stB(0, 1, 0);
  stB(1, 0, 1); stB(1, 1, 1);
  asm volatile("s_waitcnt vmcnt(4)" ::: "memory");
  SBAR_; HBAR_; SBAR_;
  RDA(0, 0, arC); RDB(0, 0, brE);
  SBAR_;

  for (int t = 0; t < nt; t += 2) {
    TILE8(t, brE, brO);
    TILE8(t + 1, brO, brE);
  }

  // epilogue: 16x16x32 C-layout col=lane&15, row=(lane>>4)*4+r
#pragma unroll
  for (int mfg = 0; mfg < 8; ++mfg)
#pragma unroll
    for (int nfg = 0; nfg < 4; ++nfg) {
      const int col = col0 + wn * 64 + (nfg >> 1) * 32 + (nfg & 1) * 16 + fr;
#pragma unroll
      for (int r = 0; r < 4; ++r) {
        const int row = row0 + wm * 128 + mfg * 16 + fq * 4 + r;
        C[(size_t)row * N + col] = (CT)acc[mfg][nfg][r];
      }
    }
}

// ---------------- fused in-place RoPE for q_comb and kv_comb rope slices (1 launch) ----------------
#define QROPE_BLOCKS ((B_ * LQ * H_) / 8)
__global__ __launch_bounds__(256) void rope2_kernel(bf16_t* __restrict__ qbase, bf16_t* __restrict__ kvbase) {
  const int bid = blockIdx.x;
  bf16_t* base;
  int tokStride, hshift, posMask;
  long bidl;
  if (bid < QROPE_BLOCKS) { base = qbase; tokStride = QCOMB; hshift = 4; posMask = LQ - 1; bidl = bid; }
  else { base = kvbase; tokStride = KCOMB; hshift = 0; posMask = LK - 1; bidl = bid - QROPE_BLOCKS; }
  const long idx = bidl * 8 + (threadIdx.x >> 5);  // tok*heads + h
  const int i = threadIdx.x & 31;
  const long tok = idx >> hshift;
  const int h = (int)(idx & ((1 << hshift) - 1));
  const int pos = (int)(tok & posMask);
  bf16_t* p = base + tok * (long)tokStride + h * 64;
  const float x1 = (float)p[i], x2 = (float)p[i + 32];
  const float invf = expf(-((float)i * (1.0f / 32.f)) * 9.210340371976184f);  // ln(10000)
  float sn, cs;
  sincosf((float)pos * invf, &sn, &cs);
  p[i]      = (bf16_t)(x1 * cs - x2 * sn);
  p[i + 32] = (bf16_t)(x1 * sn + x2 * cs);
}

// ---------------- sparse windowed attention: <=9 keys per query ----------------
__global__ __launch_bounds__(256) void attn_sparse(
    const bf16_t* __restrict__ qc, const bf16_t* __restrict__ kvc,
    const int* __restrict__ seg, bf16_t* __restrict__ out) {
  const int qrow = blockIdx.x * 4 + (threadIdx.x >> 6);  // b*LQ + qi
  const int lane = threadIdx.x & 63;
  const int h = lane >> 2, sub = lane & 3;
  const int b = qrow >> 12;  // / LQ
  const int s = seg[qrow];
  const int kl = max(0, s - 8);
  const float scale = 0.07216878364870322f;  // 1/sqrt(HD+R)

  float qnf[32], qrf[16];
  {
    const bf16_t* p = qc + (size_t)qrow * QCOMB + h * HD_ + sub * 32;
#pragma unroll
    for (int j = 0; j < 4; ++j) {
      bf16x8 t = *(const bf16x8*)(p + j * 8);
#pragma unroll
      for (int e = 0; e < 8; ++e) qnf[j * 8 + e] = (float)t[e];
    }
    const bf16_t* p2 = qc + (size_t)qrow * QCOMB + 2048 + h * R_ + sub * 16;
#pragma unroll
    for (int j = 0; j < 2; ++j) {
      bf16x8 t = *(const bf16x8*)(p2 + j * 8);
#pragma unroll
      for (int e = 0; e < 8; ++e) qrf[j * 8 + e] = (float)t[e];
    }
  }

  float sc[9];
#pragma unroll
  for (int kk = 0; kk < 9; ++kk) {
    const int kx = kl + kk;
    const bf16_t* kb = kvc + (size_t)(b * LK + kx) * KCOMB;
    float d = 0.f;
    const bf16_t* p = kb + h * HD_ + sub * 32;
#pragma unroll
    for (int j = 0; j < 4; ++j) {
      bf16x8 t = *(const bf16x8*)(p + j * 8);
#pragma unroll
      for (int e = 0; e < 8; ++e) d += qnf[j * 8 + e] * (float)t[e];
    }
    const bf16_t* p2 = kb + 4096 + sub * 16;
#pragma unroll
    for (int j = 0; j < 2; ++j) {
      bf16x8 t = *(const bf16x8*)(p2 + j * 8);
#pragma unroll
      for (int e = 0; e < 8; ++e) d += qrf[j * 8 + e] * (float)t[e];
    }
    d += __shfl_xor(d, 1);
    d += __shfl_xor(d, 2);
    sc[kk] = (kx <= s) ? d * scale : -1e30f;
  }
  float m = sc[0];
#pragma unroll
  for (int kk = 1; kk < 9; ++kk) m = fmaxf(m, sc[kk]);
  float sum = 0.f;
#pragma unroll
  for (int kk = 0; kk < 9; ++kk) { const float p = expf(sc[kk] - m); sc[kk] = p; sum += p; }
  const float inv = 1.f / sum;

  float o[32];
#pragma unroll
  for (int j = 0; j < 32; ++j) o[j] = 0.f;
#pragma unroll
  for (int kk = 0; kk < 9; ++kk) {
    const bf16_t* pv = kvc + (size_t)(b * LK + kl + kk) * KCOMB + 2048 + h * HD_ + sub * 32;
    const float p = sc[kk] * inv;
#pragma unroll
    for (int j = 0; j < 4; ++j) {
      bf16x8 t = *(const bf16x8*)(pv + j * 8);
#pragma unroll
      for (int e = 0; e < 8; ++e) o[j * 8 + e] += p * (float)t[e];
    }
  }
  bf16_t* po = out + (size_t)qrow * (H_ * HD_) + h * HD_ + sub * 32;
#pragma unroll
  for (int j = 0; j < 4; ++j) {
    bf16x8 t;
#pragma unroll
    for (int e = 0; e < 8; ++e) t[e] = (bf16_t)o[j * 8 + e];
    *(bf16x8*)(po + j * 8) = t;
  }
}

extern "C" void kernel_launch(void* const* d_in, const int* in_sizes, int n_in,
                              void* d_out, int out_size, void* d_ws, size_t ws_size,
                              hipStream_t stream) {
  const float* q     = (const float*)d_in[0];
  const float* kv    = (const float*)d_in[1];
  const int*   seg   = (const int*)d_in[2];
  const float* W_kvc = (const float*)d_in[3];
  const float* W_dq  = (const float*)d_in[4];
  const float* W_uq  = (const float*)d_in[5];
  const float* W_qr  = (const float*)d_in[6];
  const float* W_uk  = (const float*)d_in[7];
  const float* W_kr  = (const float*)d_in[8];
  const float* W_uv  = (const float*)d_in[9];
  const float* W_o   = (const float*)d_in[10];
  float* out = (float*)d_out;
  (void)in_sizes; (void)n_in; (void)out_size; (void)ws_size;

  char* ws = (char*)d_ws;
  size_t off = 0;
  auto alloc = [&](size_t bytes) {
    char* p = ws + off;
    off = (off + bytes + 255) & ~(size_t)255;
    return p;
  };
  bf16_t* q_bf    = (bf16_t*)alloc((size_t)B_ * LQ * QDIM * 2);   // reused as attn_o
  bf16_t* kv_bf   = (bf16_t*)alloc((size_t)B_ * LK * KVDIM * 2);
  bf16_t* WkvcT   = (bf16_t*)alloc((size_t)KVC_ * KVDIM * 2);
  bf16_t* WdqT    = (bf16_t*)alloc((size_t)QC_ * QDIM * 2);
  bf16_t* WuqrT   = (bf16_t*)alloc((size_t)QCOMB * QC_ * 2);      // [W_uq^T ; W_qr^T]
  bf16_t* WkvT    = (bf16_t*)alloc((size_t)KCOMB * KVC_ * 2);     // [W_uk^T ; W_uv^T ; W_kr^T ; pad]
  bf16_t* WoT     = (bf16_t*)alloc((size_t)QDIM * (H_ * HD_) * 2);
  bf16_t* kv_c    = (bf16_t*)alloc((size_t)B_ * LK * KVC_ * 2);
  bf16_t* q_c     = (bf16_t*)alloc((size_t)B_ * LQ * QC_ * 2);
  bf16_t* q_comb  = (bf16_t*)alloc((size_t)B_ * LQ * QCOMB * 2);
  bf16_t* kv_comb = (bf16_t*)alloc((size_t)B_ * LK * KCOMB * 2);
  bf16_t* attn_o  = q_bf;  // q_bf dead after q_c GEMM

  // ---- convert inputs to bf16 (1 launch) ----
  cvt2_f32_bf16<<<4096, 256, 0, stream>>>(q, q_bf, (long)B_ * LQ * QDIM,
                                          kv, kv_bf, (long)B_ * LK * KVDIM);

  // ---- transpose+convert ALL weights (1 launch) ----
  {
    TransAll d;
    auto set = [&](int i, const float* s, bf16_t* dt, int K, int N) {
      d.src[i] = s; d.dst[i] = dt; d.K[i] = K; d.N[i] = N; d.gx[i] = N / 32;
    };
    set(0, W_kvc, WkvcT, KVDIM, KVC_);
    set(1, W_dq,  WdqT,  QDIM,  QC_);
    set(2, W_uq,  WuqrT, QC_,   H_ * HD_);
    set(3, W_qr,  WuqrT + (size_t)(H_ * HD_) * QC_, QC_, H_ * R_);
    set(4, W_uk,  WkvT,  KVC_,  H_ * HD_);
    set(5, W_uv,  WkvT + (size_t)(H_ * HD_) * KVC_, KVC_, H_ * HD_);
    set(6, W_kr,  WkvT + (size_t)2 * (H_ * HD_) * KVC_, KVC_, R_);
    set(7, W_o,   WoT,   H_ * HD_, QDIM);
    int acc_off = 0;
    for (int i = 0; i < 8; ++i) {
      d.off[i] = acc_off;
      acc_off += (d.N[i] / 32) * (d.K[i] / 32);
    }
    d.off[8] = acc_off;
    transpose_all<<<acc_off, dim3(32, 8), 0, stream>>>(d);
  }

  // ---- projection GEMMs (C = A @ Bt^T) ----
  gemm_bt<bf16_t><<<dim3(KVC_ / 128, (B_ * LK) / 128), 256, 0, stream>>>(
      kv_bf, WkvcT, kv_c, B_ * LK, KVC_, KVDIM);
  gemm_big2<128, bf16_t><<<dim3(QC_ / 128, (B_ * LQ) / 256), 512, 0, stream>>>(
      q_bf, WdqT, q_c, B_ * LQ, QC_, QDIM);
  gemm_8ph<bf16_t><<<dim3(QCOMB / 256, (B_ * LQ) / 256), 512, 0, stream>>>(
      q_c, WuqrT, q_comb, B_ * LQ, QCOMB, QC_);
  gemm_big2<128, bf16_t><<<dim3(KCOMB / 128, (B_ * LK) / 256), 512, 0, stream>>>(
      kv_c, WkvT, kv_comb, B_ * LK, KCOMB, KVC_);

  // ---- fused RoPE (q + kv slices, 1 launch) ----
  rope2_kernel<<<QROPE_BLOCKS + (B_ * LK) / 8, 256, 0, stream>>>(q_comb + 2048, kv_comb + 4096);

  // ---- sparse attention (<=9 keys/query) ----
  attn_sparse<<<(B_ * LQ) / 4, 256, 0, stream>>>(q_comb, kv_comb, seg, attn_o);

  // ---- output projection ----
  gemm_8ph<float><<<dim3(QDIM / 256, (B_ * LQ) / 256), 512, 0, stream>>>(
      attn_o, WoT, out, B_ * LQ, QDIM, H_ * HD_);
}

// Round 9
// 299.058 us; speedup vs baseline: 1.3102x; 1.3102x over previous
//
#include <hip/hip_runtime.h>
#include <math.h>

typedef __bf16 bf16_t;
typedef __bf16 bf16x8 __attribute__((ext_vector_type(8)));
typedef float f32x4 __attribute__((ext_vector_type(4)));

#define B_    2
#define LQ    4096
#define LK    1024
#define QDIM  2048
#define KVDIM 2048
#define H_    16
#define HD_   128
#define KVC_  512
#define QC_   768
#define R_    64

// fused row widths
#define QCOMB 3072   // [q_nope(2048) | q_rope(1024)]
#define KCOMB 4224   // [k_nope(2048) | v(2048) | k_rope(64) | pad(64)]

typedef __attribute__((address_space(1))) void gvoid_t;
typedef __attribute__((address_space(3))) void lvoid_t;

static __device__ __forceinline__ void gld_lds16(const void* g, void* l) {
  __builtin_amdgcn_global_load_lds((gvoid_t*)(void*)g, (lvoid_t*)l, 16, 0, 0);
}

// ---------------- fused fp32 -> bf16 convert for q and kv (1 launch) ----------------
__global__ void cvt2_f32_bf16(const float* __restrict__ a, bf16_t* __restrict__ oa, long na,
                              const float* __restrict__ b, bf16_t* __restrict__ ob, long nb) {
  const long stride = (long)gridDim.x * blockDim.x * 8;
  for (long i = ((long)blockIdx.x * blockDim.x + threadIdx.x) * 8; i < na; i += stride) {
    float4 x = *(const float4*)(a + i);
    float4 y = *(const float4*)(a + i + 4);
    bf16x8 t;
    t[0] = (bf16_t)x.x; t[1] = (bf16_t)x.y; t[2] = (bf16_t)x.z; t[3] = (bf16_t)x.w;
    t[4] = (bf16_t)y.x; t[5] = (bf16_t)y.y; t[6] = (bf16_t)y.z; t[7] = (bf16_t)y.w;
    *(bf16x8*)(oa + i) = t;
  }
  for (long i = ((long)blockIdx.x * blockDim.x + threadIdx.x) * 8; i < nb; i += stride) {
    float4 x = *(const float4*)(b + i);
    float4 y = *(const float4*)(b + i + 4);
    bf16x8 t;
    t[0] = (bf16_t)x.x; t[1] = (bf16_t)x.y; t[2] = (bf16_t)x.z; t[3] = (bf16_t)x.w;
    t[4] = (bf16_t)y.x; t[5] = (bf16_t)y.y; t[6] = (bf16_t)y.z; t[7] = (bf16_t)y.w;
    *(bf16x8*)(ob + i) = t;
  }
}

// ---------------- fused transpose+convert for ALL weights (1 launch) ----------------
struct TransAll {
  const float* src[8];
  bf16_t* dst[8];
  int K[8], N[8], gx[8];
  int off[9];
};

__global__ __launch_bounds__(256) void transpose_all(TransAll d) {
  const int bid = blockIdx.x;
  int i = 0;
#pragma unroll
  for (int j = 1; j < 8; ++j) if (bid >= d.off[j]) i = j;
  const float* __restrict__ src = d.src[i];
  bf16_t* __restrict__ dst = d.dst[i];
  const int K = d.K[i], N = d.N[i];
  const int local = bid - d.off[i];
  const int gx = d.gx[i];
  const int bx = (local % gx) * 32, by = (local / gx) * 32;
  __shared__ float t[32][33];
  const int x = threadIdx.x, y = threadIdx.y;
#pragma unroll
  for (int j = 0; j < 32; j += 8)
    t[y + j][x] = src[(size_t)(by + y + j) * N + bx + x];
  __syncthreads();
#pragma unroll
  for (int j = 0; j < 32; j += 8)
    dst[(size_t)(bx + y + j) * K + by + x] = (bf16_t)t[x][y + j];
}

// ---------------- big2 pipeline body: BM=256, BN=TN, BK=64, 8 waves (2Mx4N) ----------------
// 2 LDS buffers, counted vmcnt (never 0 mid-loop), register k-step double-buffering,
// LDS XOR swizzle via pre-swizzled global source. Requires N%TN==0, K%64==0, K/64>=2.
template <int TN, typename CT>
__device__ __forceinline__ void big2_body(
    const bf16_t* __restrict__ A, const bf16_t* __restrict__ Bt, CT* __restrict__ C,
    int N, int K, int row0, int col0, bf16_t* lA, bf16_t* lB) {
  constexpr int NF = TN / 64;
  constexpr int LW = 4 + TN / 64;
  const int tid = threadIdx.x;
  const int w = tid >> 6, lane = tid & 63;
  const int wm = w >> 2, wn = w & 3;
  const int lr = lane >> 3;
  const int kswz = ((lane & 7) ^ lr) * 8;
  const int nt = K >> 6;
  const int fr = lane & 15, fq = lane >> 4;

  auto STAGE = [&](int t, int buf) {
    const int k0 = t << 6;
#pragma unroll
    for (int j = 0; j < 4; ++j) {
      const int s = j * 8 + w;
      gld_lds16(A + (size_t)(row0 + s * 8 + lr) * K + k0 + kswz, &lA[buf * 256 * 64 + s * 512]);
    }
#pragma unroll
    for (int j = 0; j < TN / 64; ++j) {
      const int s = j * 8 + w;
      gld_lds16(Bt + (size_t)(col0 + s * 8 + lr) * K + k0 + kswz, &lB[buf * TN * 64 + s * 512]);
    }
  };

  bf16x8 aA[8], bA[NF], aB[8], bB[NF];
  f32x4 acc[8][NF];
#pragma unroll
  for (int i = 0; i < 8; ++i)
#pragma unroll
    for (int j = 0; j < NF; ++j) acc[i][j] = f32x4{0.f, 0.f, 0.f, 0.f};

  auto READ = [&](int buf, int kk, bf16x8* a, bf16x8* b) {
    const int swzk = (kk * 32 + fq * 8) ^ ((fr & 7) << 3);
#pragma unroll
    for (int mf = 0; mf < 8; ++mf)
      a[mf] = *(const bf16x8*)&lA[buf * 256 * 64 + (wm * 128 + mf * 16 + fr) * 64 + swzk];
#pragma unroll
    for (int nf = 0; nf < NF; ++nf)
      b[nf] = *(const bf16x8*)&lB[buf * TN * 64 + (wn * (TN / 4) + nf * 16 + fr) * 64 + swzk];
  };
  auto MF = [&](bf16x8* a, bf16x8* b) {
    __builtin_amdgcn_s_setprio(1);
#pragma unroll
    for (int mf = 0; mf < 8; ++mf)
#pragma unroll
      for (int nf = 0; nf < NF; ++nf)
        acc[mf][nf] = __builtin_amdgcn_mfma_f32_16x16x32_bf16(a[mf], b[nf], acc[mf][nf], 0, 0, 0);
    __builtin_amdgcn_s_setprio(0);
  };

  STAGE(0, 0);
  STAGE(1, 1);
  if constexpr (LW == 8) { asm volatile("s_waitcnt vmcnt(8)" ::: "memory"); }
  else                   { asm volatile("s_waitcnt vmcnt(6)" ::: "memory"); }
  __builtin_amdgcn_sched_barrier(0);
  __builtin_amdgcn_s_barrier();
  READ(0, 0, aA, bA);

  for (int t = 0; t < nt; ++t) {
    const int buf = t & 1;
    READ(buf, 1, aB, bB);
    __builtin_amdgcn_sched_barrier(0);
    MF(aA, bA);
    asm volatile("s_waitcnt lgkmcnt(0)" ::: "memory");
    __builtin_amdgcn_sched_barrier(0);
    __builtin_amdgcn_s_barrier();
    if (t + 2 < nt) {
      STAGE(t + 2, buf);
      if constexpr (LW == 8) { asm volatile("s_waitcnt vmcnt(8)" ::: "memory"); }
      else                   { asm volatile("s_waitcnt vmcnt(6)" ::: "memory"); }
    } else {
      asm volatile("s_waitcnt vmcnt(0)" ::: "memory");
    }
    __builtin_amdgcn_sched_barrier(0);
    __builtin_amdgcn_s_barrier();
    if (t + 1 < nt) READ(buf ^ 1, 0, aA, bA);
    __builtin_amdgcn_sched_barrier(0);
    MF(aB, bB);
  }

#pragma unroll
  for (int mf = 0; mf < 8; ++mf)
#pragma unroll
    for (int nf = 0; nf < NF; ++nf) {
      const int col = col0 + wn * (TN / 4) + nf * 16 + fr;
#pragma unroll
      for (int r = 0; r < 4; ++r) {
        const int row = row0 + wm * 128 + mf * 16 + fq * 4 + r;
        C[(size_t)row * N + col] = (CT)acc[mf][nf][r];
      }
    }
}

// ---------------- standalone big2 kernel (XCD-swizzled 2D grid) ----------------
template <int TN, typename CT>
__global__ __launch_bounds__(512, 2) void gemm_big2(
    const bf16_t* __restrict__ A, const bf16_t* __restrict__ Bt,
    CT* __restrict__ C, int M, int N, int K) {
  __shared__ __align__(16) bf16_t lA[2 * 256 * 64];
  __shared__ __align__(16) bf16_t lB[2 * TN * 64];
  const int gx = gridDim.x;
  const int nwg = gx * gridDim.y;
  const int orig = blockIdx.y * gx + blockIdx.x;
  const int wg = (orig & 7) * (nwg >> 3) + (orig >> 3);
  const int bx = wg % gx, by = wg / gx;
  big2_body<TN, CT>(A, Bt, C, N, K, by * 256, bx * TN, lA, lB);
}

// ---------------- dual big2 kernel: two independent GEMMs in one launch ----------------
// Problem 0: blocks [0, split); Problem 1: blocks [split, nwg). Branch is
// block-uniform so barriers inside the body are safe. nwg % 8 == 0 required.
__global__ __launch_bounds__(512, 2) void gemm_dual(
    const bf16_t* __restrict__ A0, const bf16_t* __restrict__ B0, bf16_t* __restrict__ C0,
    int N0, int K0,
    const bf16_t* __restrict__ A1, const bf16_t* __restrict__ B1, bf16_t* __restrict__ C1,
    int N1, int K1, int split) {
  __shared__ __align__(16) bf16_t lA[2 * 256 * 64];
  __shared__ __align__(16) bf16_t lB[2 * 128 * 64];
  const int nwg = gridDim.x;
  const int orig = blockIdx.x;
  const int wg = (orig & 7) * (nwg >> 3) + (orig >> 3);
  if (wg < split) {
    const int gx = N0 / 128;
    big2_body<128, bf16_t>(A0, B0, C0, N0, K0, (wg / gx) * 256, (wg % gx) * 128, lA, lB);
  } else {
    const int l = wg - split;
    const int gx = N1 / 128;
    big2_body<128, bf16_t>(A1, B1, C1, N1, K1, (l / gx) * 256, (l % gx) * 128, lA, lB);
  }
}

// ---------------- 8-phase GEMM (round-5 version, proven): BM=BN=256, BK=64, 8 waves ----------------
// LDS 128 KiB = 2 buf x 2 half x 128x64 x (A,B). Per K-tile: 4 phases, each =
// {ds-read quadrant frags + stage 1 half-tile -> barrier -> lgkmcnt(0) -> 16 MFMA -> barrier}.
// Stage order per tile t: ph0:A0(t+1)->buf^1  ph1:A1(t+1)->buf^1  ph2:B0(t+2)->buf  ph3:B1(t+2)->buf.
// vmcnt(4) once per K-tile at ph3 (12 outstanding -> oldest 8 = tile t+1 fully landed).
#define SWZK_(ks) (((ks) * 32 + fq * 8) ^ ((fr & 7) << 3))
#define RD_A(buf, q) { _Pragma("unroll") for (int mf = 0; mf < 4; ++mf) { \
    ar[mf][0] = *(const bf16x8*)&lA[buf][wm][((q) * 64 + mf * 16 + fr) * 64 + SWZK_(0)]; \
    ar[mf][1] = *(const bf16x8*)&lA[buf][wm][((q) * 64 + mf * 16 + fr) * 64 + SWZK_(1)]; } }
#define RD_B(buf, nq) { _Pragma("unroll") for (int nf = 0; nf < 2; ++nf) { \
    br[nq][nf][0] = *(const bf16x8*)&lB[buf][wbh][(wbr + (nq) * 32 + nf * 16 + fr) * 64 + SWZK_(0)]; \
    br[nq][nf][1] = *(const bf16x8*)&lB[buf][wbh][(wbr + (nq) * 32 + nf * 16 + fr) * 64 + SWZK_(1)]; } }
#define MFMA_Q(mq, nq) { __builtin_amdgcn_s_setprio(1); \
  _Pragma("unroll") for (int mf = 0; mf < 4; ++mf) \
  _Pragma("unroll") for (int nf = 0; nf < 2; ++nf) { \
    acc[(mq)*4+mf][(nq)*2+nf] = __builtin_amdgcn_mfma_f32_16x16x32_bf16(ar[mf][0], br[nq][nf][0], acc[(mq)*4+mf][(nq)*2+nf], 0, 0, 0); \
    acc[(mq)*4+mf][(nq)*2+nf] = __builtin_amdgcn_mfma_f32_16x16x32_bf16(ar[mf][1], br[nq][nf][1], acc[(mq)*4+mf][(nq)*2+nf], 0, 0, 0); } \
  __builtin_amdgcn_s_setprio(0); }
#define SBAR_ __builtin_amdgcn_sched_barrier(0)
#define HBAR_ __builtin_amdgcn_s_barrier()
#define LGK0_ asm volatile("s_waitcnt lgkmcnt(0)" ::: "memory")

template <typename CT>
__global__ __launch_bounds__(512, 2) void gemm_8ph(
    const bf16_t* __restrict__ A, const bf16_t* __restrict__ Bt,
    CT* __restrict__ C, int M, int N, int K) {
  __shared__ __align__(16) bf16_t lA[2][2][128 * 64];
  __shared__ __align__(16) bf16_t lB[2][2][128 * 64];
  const int tid = threadIdx.x;
  const int w = tid >> 6, lane = tid & 63;

  const int gx = gridDim.x;
  const int nwg = gx * gridDim.y;
  const int orig = blockIdx.y * gx + blockIdx.x;
  const int wg = (orig & 7) * (nwg >> 3) + (orig >> 3);
  const int bx = wg % gx, by = wg / gx;

  const int row0 = by * 256, col0 = bx * 256;
  const int wm = w >> 2, wn = w & 3;          // 2M x 4N waves, wave tile 128x64
  const int lr = lane >> 3;
  const int kswz = ((lane & 7) ^ lr) * 8;     // pre-swizzled global k-offset
  const int nt = K >> 6;
  const int fr = lane & 15, fq = lane >> 4;
  const int wbh = wn >> 1;                    // B LDS half this wave reads
  const int wbr = (wn & 1) * 64;              // row base within that half

  auto stA = [&](int t, int h, int buf) {     // stage A half-tile (128 rows x 64 k)
    const bf16_t* g = A + (size_t)(row0 + h * 128 + w * 8 + lr) * K + (t << 6) + kswz;
    gld_lds16(g, &lA[buf][h][w * 8 * 64]);
    gld_lds16(g + (size_t)64 * K, &lA[buf][h][(64 + w * 8) * 64]);
  };
  auto stB = [&](int t, int h, int buf) {
    const bf16_t* g = Bt + (size_t)(col0 + h * 128 + w * 8 + lr) * K + (t << 6) + kswz;
    gld_lds16(g, &lB[buf][h][w * 8 * 64]);
    gld_lds16(g + (size_t)64 * K, &lB[buf][h][(64 + w * 8) * 64]);
  };

  bf16x8 ar[4][2], br[2][2][2];   // A quad (reused across 2 phases), both B quads kept
  f32x4 acc[8][4];
#pragma unroll
  for (int i = 0; i < 8; ++i)
#pragma unroll
    for (int j = 0; j < 4; ++j) acc[i][j] = f32x4{0.f, 0.f, 0.f, 0.f};

  // prologue: tile 0 fully + B halves of tile 1 (A halves of tile 1 staged in tile 0's ph0/ph1)
  stA(0, 0, 0); stA(0, 1, 0); stB(0, 0, 0); stB(0, 1, 0);
  stB(1, 0, 1); stB(1, 1, 1);
  asm volatile("s_waitcnt vmcnt(4)" ::: "memory");  // tile 0's 4 halves landed
  SBAR_; HBAR_;

  for (int t = 0; t < nt; ++t) {
    const int buf = t & 1;
    // ---- ph0: read A(m0)+B(n0); stage A0(t+1) ----
    SBAR_;
    RD_A(buf, 0); RD_B(buf, 0);
    if (t + 1 < nt) stA(t + 1, 0, buf ^ 1);
    SBAR_; HBAR_; LGK0_; SBAR_;
    MFMA_Q(0, 0);
    SBAR_; HBAR_;
    // ---- ph1: read B(n1); stage A1(t+1) ----
    SBAR_;
    RD_B(buf, 1);
    if (t + 1 < nt) stA(t + 1, 1, buf ^ 1);
    SBAR_; HBAR_; LGK0_; SBAR_;
    MFMA_Q(0, 1);
    SBAR_; HBAR_;
    // ---- ph2: read A(m1); stage B0(t+2) over consumed B0 ----
    SBAR_;
    RD_A(buf, 1);
    if (t + 2 < nt) stB(t + 2, 0, buf);
    SBAR_; HBAR_; LGK0_; SBAR_;
    MFMA_Q(1, 1);
    SBAR_; HBAR_;
    // ---- ph3: no reads (B(n0) held in regs); stage B1(t+2); counted vmcnt ----
    SBAR_;
    if (t + 2 < nt) {
      stB(t + 2, 1, buf);
      asm volatile("s_waitcnt vmcnt(4)" ::: "memory");  // all of tile t+1 landed
    } else {
      asm volatile("s_waitcnt vmcnt(0)" ::: "memory");  // drain tail
    }
    SBAR_; HBAR_; SBAR_;
    MFMA_Q(1, 0);
    SBAR_; HBAR_;
  }

  // epilogue: 16x16x32 C-layout col=lane&15, row=(lane>>4)*4+r
#pragma unroll
  for (int mfg = 0; mfg < 8; ++mfg)
#pragma unroll
    for (int nfg = 0; nfg < 4; ++nfg) {
      const int col = col0 + wn * 64 + (nfg >> 1) * 32 + (nfg & 1) * 16 + fr;
#pragma unroll
      for (int r = 0; r < 4; ++r) {
        const int row = row0 + wm * 128 + mfg * 16 + fq * 4 + r;
        C[(size_t)row * N + col] = (CT)acc[mfg][nfg][r];
      }
    }
}

// ---------------- fused in-place RoPE for q_comb and kv_comb rope slices (1 launch) ----------------
#define QROPE_BLOCKS ((B_ * LQ * H_) / 8)
__global__ __launch_bounds__(256) void rope2_kernel(bf16_t* __restrict__ qbase, bf16_t* __restrict__ kvbase) {
  const int bid = blockIdx.x;
  bf16_t* base;
  int tokStride, hshift, posMask;
  long bidl;
  if (bid < QROPE_BLOCKS) { base = qbase; tokStride = QCOMB; hshift = 4; posMask = LQ - 1; bidl = bid; }
  else { base = kvbase; tokStride = KCOMB; hshift = 0; posMask = LK - 1; bidl = bid - QROPE_BLOCKS; }
  const long idx = bidl * 8 + (threadIdx.x >> 5);  // tok*heads + h
  const int i = threadIdx.x & 31;
  const long tok = idx >> hshift;
  const int h = (int)(idx & ((1 << hshift) - 1));
  const int pos = (int)(tok & posMask);
  bf16_t* p = base + tok * (long)tokStride + h * 64;
  const float x1 = (float)p[i], x2 = (float)p[i + 32];
  const float invf = expf(-((float)i * (1.0f / 32.f)) * 9.210340371976184f);  // ln(10000)
  float sn, cs;
  sincosf((float)pos * invf, &sn, &cs);
  p[i]      = (bf16_t)(x1 * cs - x2 * sn);
  p[i + 32] = (bf16_t)(x1 * sn + x2 * cs);
}

// ---------------- sparse windowed attention: <=9 keys per query ----------------
__global__ __launch_bounds__(256) void attn_sparse(
    const bf16_t* __restrict__ qc, const bf16_t* __restrict__ kvc,
    const int* __restrict__ seg, bf16_t* __restrict__ out) {
  const int qrow = blockIdx.x * 4 + (threadIdx.x >> 6);  // b*LQ + qi
  const int lane = threadIdx.x & 63;
  const int h = lane >> 2, sub = lane & 3;
  const int b = qrow >> 12;  // / LQ
  const int s = seg[qrow];
  const int kl = max(0, s - 8);
  const float scale = 0.07216878364870322f;  // 1/sqrt(HD+R)

  float qnf[32], qrf[16];
  {
    const bf16_t* p = qc + (size_t)qrow * QCOMB + h * HD_ + sub * 32;
#pragma unroll
    for (int j = 0; j < 4; ++j) {
      bf16x8 t = *(const bf16x8*)(p + j * 8);
#pragma unroll
      for (int e = 0; e < 8; ++e) qnf[j * 8 + e] = (float)t[e];
    }
    const bf16_t* p2 = qc + (size_t)qrow * QCOMB + 2048 + h * R_ + sub * 16;
#pragma unroll
    for (int j = 0; j < 2; ++j) {
      bf16x8 t = *(const bf16x8*)(p2 + j * 8);
#pragma unroll
      for (int e = 0; e < 8; ++e) qrf[j * 8 + e] = (float)t[e];
    }
  }

  float sc[9];
#pragma unroll
  for (int kk = 0; kk < 9; ++kk) {
    const int kx = kl + kk;
    const bf16_t* kb = kvc + (size_t)(b * LK + kx) * KCOMB;
    float d = 0.f;
    const bf16_t* p = kb + h * HD_ + sub * 32;
#pragma unroll
    for (int j = 0; j < 4; ++j) {
      bf16x8 t = *(const bf16x8*)(p + j * 8);
#pragma unroll
      for (int e = 0; e < 8; ++e) d += qnf[j * 8 + e] * (float)t[e];
    }
    const bf16_t* p2 = kb + 4096 + sub * 16;
#pragma unroll
    for (int j = 0; j < 2; ++j) {
      bf16x8 t = *(const bf16x8*)(p2 + j * 8);
#pragma unroll
      for (int e = 0; e < 8; ++e) d += qrf[j * 8 + e] * (float)t[e];
    }
    d += __shfl_xor(d, 1);
    d += __shfl_xor(d, 2);
    sc[kk] = (kx <= s) ? d * scale : -1e30f;
  }
  float m = sc[0];
#pragma unroll
  for (int kk = 1; kk < 9; ++kk) m = fmaxf(m, sc[kk]);
  float sum = 0.f;
#pragma unroll
  for (int kk = 0; kk < 9; ++kk) { const float p = expf(sc[kk] - m); sc[kk] = p; sum += p; }
  const float inv = 1.f / sum;

  float o[32];
#pragma unroll
  for (int j = 0; j < 32; ++j) o[j] = 0.f;
#pragma unroll
  for (int kk = 0; kk < 9; ++kk) {
    const bf16_t* pv = kvc + (size_t)(b * LK + kl + kk) * KCOMB + 2048 + h * HD_ + sub * 32;
    const float p = sc[kk] * inv;
#pragma unroll
    for (int j = 0; j < 4; ++j) {
      bf16x8 t = *(const bf16x8*)(pv + j * 8);
#pragma unroll
      for (int e = 0; e < 8; ++e) o[j * 8 + e] += p * (float)t[e];
    }
  }
  bf16_t* po = out + (size_t)qrow * (H_ * HD_) + h * HD_ + sub * 32;
#pragma unroll
  for (int j = 0; j < 4; ++j) {
    bf16x8 t;
#pragma unroll
    for (int e = 0; e < 8; ++e) t[e] = (bf16_t)o[j * 8 + e];
    *(bf16x8*)(po + j * 8) = t;
  }
}

extern "C" void kernel_launch(void* const* d_in, const int* in_sizes, int n_in,
                              void* d_out, int out_size, void* d_ws, size_t ws_size,
                              hipStream_t stream) {
  const float* q     = (const float*)d_in[0];
  const float* kv    = (const float*)d_in[1];
  const int*   seg   = (const int*)d_in[2];
  const float* W_kvc = (const float*)d_in[3];
  const float* W_dq  = (const float*)d_in[4];
  const float* W_uq  = (const float*)d_in[5];
  const float* W_qr  = (const float*)d_in[6];
  const float* W_uk  = (const float*)d_in[7];
  const float* W_kr  = (const float*)d_in[8];
  const float* W_uv  = (const float*)d_in[9];
  const float* W_o   = (const float*)d_in[10];
  float* out = (float*)d_out;
  (void)in_sizes; (void)n_in; (void)out_size; (void)ws_size;

  char* ws = (char*)d_ws;
  size_t off = 0;
  auto alloc = [&](size_t bytes) {
    char* p = ws + off;
    off = (off + bytes + 255) & ~(size_t)255;
    return p;
  };
  bf16_t* q_bf    = (bf16_t*)alloc((size_t)B_ * LQ * QDIM * 2);   // reused as attn_o
  bf16_t* kv_bf   = (bf16_t*)alloc((size_t)B_ * LK * KVDIM * 2);
  bf16_t* WkvcT   = (bf16_t*)alloc((size_t)KVC_ * KVDIM * 2);
  bf16_t* WdqT    = (bf16_t*)alloc((size_t)QC_ * QDIM * 2);
  bf16_t* WuqrT   = (bf16_t*)alloc((size_t)QCOMB * QC_ * 2);      // [W_uq^T ; W_qr^T]
  bf16_t* WkvT    = (bf16_t*)alloc((size_t)KCOMB * KVC_ * 2);     // [W_uk^T ; W_uv^T ; W_kr^T ; pad]
  bf16_t* WoT     = (bf16_t*)alloc((size_t)QDIM * (H_ * HD_) * 2);
  bf16_t* kv_c    = (bf16_t*)alloc((size_t)B_ * LK * KVC_ * 2);
  bf16_t* q_c     = (bf16_t*)alloc((size_t)B_ * LQ * QC_ * 2);
  bf16_t* q_comb  = (bf16_t*)alloc((size_t)B_ * LQ * QCOMB * 2);
  bf16_t* kv_comb = (bf16_t*)alloc((size_t)B_ * LK * KCOMB * 2);
  bf16_t* attn_o  = q_bf;  // q_bf dead after q_c GEMM

  // ---- convert inputs to bf16 (1 launch) ----
  cvt2_f32_bf16<<<4096, 256, 0, stream>>>(q, q_bf, (long)B_ * LQ * QDIM,
                                          kv, kv_bf, (long)B_ * LK * KVDIM);

  // ---- transpose+convert ALL weights (1 launch) ----
  {
    TransAll d;
    auto set = [&](int i, const float* s, bf16_t* dt, int K, int N) {
      d.src[i] = s; d.dst[i] = dt; d.K[i] = K; d.N[i] = N; d.gx[i] = N / 32;
    };
    set(0, W_kvc, WkvcT, KVDIM, KVC_);
    set(1, W_dq,  WdqT,  QDIM,  QC_);
    set(2, W_uq,  WuqrT, QC_,   H_ * HD_);
    set(3, W_qr,  WuqrT + (size_t)(H_ * HD_) * QC_, QC_, H_ * R_);
    set(4, W_uk,  WkvT,  KVC_,  H_ * HD_);
    set(5, W_uv,  WkvT + (size_t)(H_ * HD_) * KVC_, KVC_, H_ * HD_);
    set(6, W_kr,  WkvT + (size_t)2 * (H_ * HD_) * KVC_, KVC_, R_);
    set(7, W_o,   WoT,   H_ * HD_, QDIM);
    int acc_off = 0;
    for (int i = 0; i < 8; ++i) {
      d.off[i] = acc_off;
      acc_off += (d.N[i] / 32) * (d.K[i] / 32);
    }
    d.off[8] = acc_off;
    transpose_all<<<acc_off, dim3(32, 8), 0, stream>>>(d);
  }

  // ---- fused kv_c + q_dq GEMM (independent; one launch fills the machine) ----
  // kv_c: M=2048,N=512,K=2048 -> 32 blocks; q_dq: M=8192,N=768,K=2048 -> 192 blocks
  gemm_dual<<<224, 512, 0, stream>>>(
      kv_bf, WkvcT, kv_c, KVC_, KVDIM,
      q_bf, WdqT, q_c, QC_, QDIM, 32);

  // ---- up-projections ----
  gemm_8ph<bf16_t><<<dim3(QCOMB / 256, (B_ * LQ) / 256), 512, 0, stream>>>(
      q_c, WuqrT, q_comb, B_ * LQ, QCOMB, QC_);
  gemm_big2<128, bf16_t><<<dim3(KCOMB / 128, (B_ * LK) / 256), 512, 0, stream>>>(
      kv_c, WkvT, kv_comb, B_ * LK, KCOMB, KVC_);

  // ---- fused RoPE (q + kv slices, 1 launch) ----
  rope2_kernel<<<QROPE_BLOCKS + (B_ * LK) / 8, 256, 0, stream>>>(q_comb + 2048, kv_comb + 4096);

  // ---- sparse attention (<=9 keys/query) ----
  attn_sparse<<<(B_ * LQ) / 4, 256, 0, stream>>>(q_comb, kv_comb, seg, attn_o);

  // ---- output projection ----
  gemm_8ph<float><<<dim3(QDIM / 256, (B_ * LQ) / 256), 512, 0, stream>>>(
      attn_o, WoT, out, B_ * LQ, QDIM, H_ * HD_);
}

// Round 10
// 298.448 us; speedup vs baseline: 1.3129x; 1.0020x over previous
//
#include <hip/hip_runtime.h>
#include <math.h>

typedef __bf16 bf16_t;
typedef __bf16 bf16x8 __attribute__((ext_vector_type(8)));
typedef float f32x4 __attribute__((ext_vector_type(4)));

#define B_    2
#define LQ    4096
#define LK    1024
#define QDIM  2048
#define KVDIM 2048
#define H_    16
#define HD_   128
#define KVC_  512
#define QC_   768
#define R_    64

// fused row widths
#define QCOMB 3072   // [q_nope(2048) | q_rope(1024)]
#define KCOMB 4224   // [k_nope(2048) | v(2048) | k_rope(64) | pad(64)]

typedef __attribute__((address_space(1))) void gvoid_t;
typedef __attribute__((address_space(3))) void lvoid_t;

static __device__ __forceinline__ void gld_lds16(const void* g, void* l) {
  __builtin_amdgcn_global_load_lds((gvoid_t*)(void*)g, (lvoid_t*)l, 16, 0, 0);
}

// ---------------- fused fp32 -> bf16 convert for q and kv (1 launch) ----------------
__global__ void cvt2_f32_bf16(const float* __restrict__ a, bf16_t* __restrict__ oa, long na,
                              const float* __restrict__ b, bf16_t* __restrict__ ob, long nb) {
  const long stride = (long)gridDim.x * blockDim.x * 8;
  for (long i = ((long)blockIdx.x * blockDim.x + threadIdx.x) * 8; i < na; i += stride) {
    float4 x = *(const float4*)(a + i);
    float4 y = *(const float4*)(a + i + 4);
    bf16x8 t;
    t[0] = (bf16_t)x.x; t[1] = (bf16_t)x.y; t[2] = (bf16_t)x.z; t[3] = (bf16_t)x.w;
    t[4] = (bf16_t)y.x; t[5] = (bf16_t)y.y; t[6] = (bf16_t)y.z; t[7] = (bf16_t)y.w;
    *(bf16x8*)(oa + i) = t;
  }
  for (long i = ((long)blockIdx.x * blockDim.x + threadIdx.x) * 8; i < nb; i += stride) {
    float4 x = *(const float4*)(b + i);
    float4 y = *(const float4*)(b + i + 4);
    bf16x8 t;
    t[0] = (bf16_t)x.x; t[1] = (bf16_t)x.y; t[2] = (bf16_t)x.z; t[3] = (bf16_t)x.w;
    t[4] = (bf16_t)y.x; t[5] = (bf16_t)y.y; t[6] = (bf16_t)y.z; t[7] = (bf16_t)y.w;
    *(bf16x8*)(ob + i) = t;
  }
}

// ---------------- fused transpose+convert for ALL weights (1 launch) ----------------
struct TransAll {
  const float* src[8];
  bf16_t* dst[8];
  int K[8], N[8], gx[8];
  int off[9];
};

__global__ __launch_bounds__(256) void transpose_all(TransAll d) {
  const int bid = blockIdx.x;
  int i = 0;
#pragma unroll
  for (int j = 1; j < 8; ++j) if (bid >= d.off[j]) i = j;
  const float* __restrict__ src = d.src[i];
  bf16_t* __restrict__ dst = d.dst[i];
  const int K = d.K[i], N = d.N[i];
  const int local = bid - d.off[i];
  const int gx = d.gx[i];
  const int bx = (local % gx) * 32, by = (local / gx) * 32;
  __shared__ float t[32][33];
  const int x = threadIdx.x, y = threadIdx.y;
#pragma unroll
  for (int j = 0; j < 32; j += 8)
    t[y + j][x] = src[(size_t)(by + y + j) * N + bx + x];
  __syncthreads();
#pragma unroll
  for (int j = 0; j < 32; j += 8)
    dst[(size_t)(bx + y + j) * K + by + x] = (bf16_t)t[x][y + j];
}

// ---------------- big2 pipeline body: BM=256, BN=TN, BK=64, 8 waves (2Mx4N) ----------------
template <int TN, typename CT>
__device__ __forceinline__ void big2_body(
    const bf16_t* __restrict__ A, const bf16_t* __restrict__ Bt, CT* __restrict__ C,
    int N, int K, int row0, int col0, bf16_t* lA, bf16_t* lB) {
  constexpr int NF = TN / 64;
  constexpr int LW = 4 + TN / 64;
  const int tid = threadIdx.x;
  const int w = tid >> 6, lane = tid & 63;
  const int wm = w >> 2, wn = w & 3;
  const int lr = lane >> 3;
  const int kswz = ((lane & 7) ^ lr) * 8;
  const int nt = K >> 6;
  const int fr = lane & 15, fq = lane >> 4;

  auto STAGE = [&](int t, int buf) {
    const int k0 = t << 6;
#pragma unroll
    for (int j = 0; j < 4; ++j) {
      const int s = j * 8 + w;
      gld_lds16(A + (size_t)(row0 + s * 8 + lr) * K + k0 + kswz, &lA[buf * 256 * 64 + s * 512]);
    }
#pragma unroll
    for (int j = 0; j < TN / 64; ++j) {
      const int s = j * 8 + w;
      gld_lds16(Bt + (size_t)(col0 + s * 8 + lr) * K + k0 + kswz, &lB[buf * TN * 64 + s * 512]);
    }
  };

  bf16x8 aA[8], bA[NF], aB[8], bB[NF];
  f32x4 acc[8][NF];
#pragma unroll
  for (int i = 0; i < 8; ++i)
#pragma unroll
    for (int j = 0; j < NF; ++j) acc[i][j] = f32x4{0.f, 0.f, 0.f, 0.f};

  auto READ = [&](int buf, int kk, bf16x8* a, bf16x8* b) {
    const int swzk = (kk * 32 + fq * 8) ^ ((fr & 7) << 3);
#pragma unroll
    for (int mf = 0; mf < 8; ++mf)
      a[mf] = *(const bf16x8*)&lA[buf * 256 * 64 + (wm * 128 + mf * 16 + fr) * 64 + swzk];
#pragma unroll
    for (int nf = 0; nf < NF; ++nf)
      b[nf] = *(const bf16x8*)&lB[buf * TN * 64 + (wn * (TN / 4) + nf * 16 + fr) * 64 + swzk];
  };
  auto MF = [&](bf16x8* a, bf16x8* b) {
    __builtin_amdgcn_s_setprio(1);
#pragma unroll
    for (int mf = 0; mf < 8; ++mf)
#pragma unroll
      for (int nf = 0; nf < NF; ++nf)
        acc[mf][nf] = __builtin_amdgcn_mfma_f32_16x16x32_bf16(a[mf], b[nf], acc[mf][nf], 0, 0, 0);
    __builtin_amdgcn_s_setprio(0);
  };

  STAGE(0, 0);
  STAGE(1, 1);
  if constexpr (LW == 8) { asm volatile("s_waitcnt vmcnt(8)" ::: "memory"); }
  else                   { asm volatile("s_waitcnt vmcnt(6)" ::: "memory"); }
  __builtin_amdgcn_sched_barrier(0);
  __builtin_amdgcn_s_barrier();
  READ(0, 0, aA, bA);

  for (int t = 0; t < nt; ++t) {
    const int buf = t & 1;
    READ(buf, 1, aB, bB);
    __builtin_amdgcn_sched_barrier(0);
    MF(aA, bA);
    asm volatile("s_waitcnt lgkmcnt(0)" ::: "memory");
    __builtin_amdgcn_sched_barrier(0);
    __builtin_amdgcn_s_barrier();
    if (t + 2 < nt) {
      STAGE(t + 2, buf);
      if constexpr (LW == 8) { asm volatile("s_waitcnt vmcnt(8)" ::: "memory"); }
      else                   { asm volatile("s_waitcnt vmcnt(6)" ::: "memory"); }
    } else {
      asm volatile("s_waitcnt vmcnt(0)" ::: "memory");
    }
    __builtin_amdgcn_sched_barrier(0);
    __builtin_amdgcn_s_barrier();
    if (t + 1 < nt) READ(buf ^ 1, 0, aA, bA);
    __builtin_amdgcn_sched_barrier(0);
    MF(aB, bB);
  }

#pragma unroll
  for (int mf = 0; mf < 8; ++mf)
#pragma unroll
    for (int nf = 0; nf < NF; ++nf) {
      const int col = col0 + wn * (TN / 4) + nf * 16 + fr;
#pragma unroll
      for (int r = 0; r < 4; ++r) {
        const int row = row0 + wm * 128 + mf * 16 + fq * 4 + r;
        C[(size_t)row * N + col] = (CT)acc[mf][nf][r];
      }
    }
}

// ---------------- standalone big2 kernel (XCD-swizzled 2D grid) ----------------
template <int TN, typename CT>
__global__ __launch_bounds__(512, 2) void gemm_big2(
    const bf16_t* __restrict__ A, const bf16_t* __restrict__ Bt,
    CT* __restrict__ C, int M, int N, int K) {
  __shared__ __align__(16) bf16_t lA[2 * 256 * 64];
  __shared__ __align__(16) bf16_t lB[2 * TN * 64];
  const int gx = gridDim.x;
  const int nwg = gx * gridDim.y;
  const int orig = blockIdx.y * gx + blockIdx.x;
  const int wg = (orig & 7) * (nwg >> 3) + (orig >> 3);
  const int bx = wg % gx, by = wg / gx;
  big2_body<TN, CT>(A, Bt, C, N, K, by * 256, bx * TN, lA, lB);
}

// ---------------- dual big2 kernel: two independent GEMMs in one launch ----------------
__global__ __launch_bounds__(512, 2) void gemm_dual(
    const bf16_t* __restrict__ A0, const bf16_t* __restrict__ B0, bf16_t* __restrict__ C0,
    int N0, int K0,
    const bf16_t* __restrict__ A1, const bf16_t* __restrict__ B1, bf16_t* __restrict__ C1,
    int N1, int K1, int split) {
  __shared__ __align__(16) bf16_t lA[2 * 256 * 64];
  __shared__ __align__(16) bf16_t lB[2 * 128 * 64];
  const int nwg = gridDim.x;
  const int orig = blockIdx.x;
  const int wg = (orig & 7) * (nwg >> 3) + (orig >> 3);
  if (wg < split) {
    const int gx = N0 / 128;
    big2_body<128, bf16_t>(A0, B0, C0, N0, K0, (wg / gx) * 256, (wg % gx) * 128, lA, lB);
  } else {
    const int l = wg - split;
    const int gx = N1 / 128;
    big2_body<128, bf16_t>(A1, B1, C1, N1, K1, (l / gx) * 256, (l % gx) * 128, lA, lB);
  }
}

// ---------------- 8-phase GEMM: r5 skeleton, compiler-counted lgkmcnt ----------------
// BM=BN=256, BK=64, 8 waves. LDS 128 KiB = 2 buf x 2 half x 128x64 x (A,B).
// Per K-tile: 4 phases = {ds-read quadrant frags + stage 1 half-tile -> barrier ->
// 16 MFMA -> barrier}. CHANGE vs r5: no explicit lgkmcnt(0) before the MFMA cluster —
// reads are plain C++ loads, so the compiler emits progressive counted lgkmcnt per
// dependent MFMA operand and the LDS drain overlaps the MFMA cluster (m97 behavior).
// Correctness: each region's reads complete before that phase's closing s_barrier
// (consuming MFMA proves completion); its overwriting stage is >=1 closing barrier
// later. vmcnt ledger unchanged: vmcnt(4) once per K-tile at ph3.
#define SWZK_(ks) (((ks) * 32 + fq * 8) ^ ((fr & 7) << 3))
#define RD_A(buf, q) { _Pragma("unroll") for (int mf = 0; mf < 4; ++mf) { \
    ar[mf][0] = *(const bf16x8*)&lA[buf][wm][((q) * 64 + mf * 16 + fr) * 64 + SWZK_(0)]; \
    ar[mf][1] = *(const bf16x8*)&lA[buf][wm][((q) * 64 + mf * 16 + fr) * 64 + SWZK_(1)]; } }
#define RD_B(buf, nq) { _Pragma("unroll") for (int nf = 0; nf < 2; ++nf) { \
    br[nq][nf][0] = *(const bf16x8*)&lB[buf][wbh][(wbr + (nq) * 32 + nf * 16 + fr) * 64 + SWZK_(0)]; \
    br[nq][nf][1] = *(const bf16x8*)&lB[buf][wbh][(wbr + (nq) * 32 + nf * 16 + fr) * 64 + SWZK_(1)]; } }
#define MFMA_Q(mq, nq) { __builtin_amdgcn_s_setprio(1); \
  _Pragma("unroll") for (int mf = 0; mf < 4; ++mf) \
  _Pragma("unroll") for (int nf = 0; nf < 2; ++nf) { \
    acc[(mq)*4+mf][(nq)*2+nf] = __builtin_amdgcn_mfma_f32_16x16x32_bf16(ar[mf][0], br[nq][nf][0], acc[(mq)*4+mf][(nq)*2+nf], 0, 0, 0); \
    acc[(mq)*4+mf][(nq)*2+nf] = __builtin_amdgcn_mfma_f32_16x16x32_bf16(ar[mf][1], br[nq][nf][1], acc[(mq)*4+mf][(nq)*2+nf], 0, 0, 0); } \
  __builtin_amdgcn_s_setprio(0); }
#define SBAR_ __builtin_amdgcn_sched_barrier(0)
#define HBAR_ __builtin_amdgcn_s_barrier()

template <typename CT>
__global__ __launch_bounds__(512, 2) void gemm_8ph(
    const bf16_t* __restrict__ A, const bf16_t* __restrict__ Bt,
    CT* __restrict__ C, int M, int N, int K) {
  __shared__ __align__(16) bf16_t lA[2][2][128 * 64];
  __shared__ __align__(16) bf16_t lB[2][2][128 * 64];
  const int tid = threadIdx.x;
  const int w = tid >> 6, lane = tid & 63;

  const int gx = gridDim.x;
  const int nwg = gx * gridDim.y;
  const int orig = blockIdx.y * gx + blockIdx.x;
  const int wg = (orig & 7) * (nwg >> 3) + (orig >> 3);
  const int bx = wg % gx, by = wg / gx;

  const int row0 = by * 256, col0 = bx * 256;
  const int wm = w >> 2, wn = w & 3;          // 2M x 4N waves, wave tile 128x64
  const int lr = lane >> 3;
  const int kswz = ((lane & 7) ^ lr) * 8;     // pre-swizzled global k-offset
  const int nt = K >> 6;
  const int fr = lane & 15, fq = lane >> 4;
  const int wbh = wn >> 1;                    // B LDS half this wave reads
  const int wbr = (wn & 1) * 64;              // row base within that half

  auto stA = [&](int t, int h, int buf) {     // stage A half-tile (128 rows x 64 k)
    const bf16_t* g = A + (size_t)(row0 + h * 128 + w * 8 + lr) * K + (t << 6) + kswz;
    gld_lds16(g, &lA[buf][h][w * 8 * 64]);
    gld_lds16(g + (size_t)64 * K, &lA[buf][h][(64 + w * 8) * 64]);
  };
  auto stB = [&](int t, int h, int buf) {
    const bf16_t* g = Bt + (size_t)(col0 + h * 128 + w * 8 + lr) * K + (t << 6) + kswz;
    gld_lds16(g, &lB[buf][h][w * 8 * 64]);
    gld_lds16(g + (size_t)64 * K, &lB[buf][h][(64 + w * 8) * 64]);
  };

  bf16x8 ar[4][2], br[2][2][2];   // A quad (reused across 2 phases), both B quads kept
  f32x4 acc[8][4];
#pragma unroll
  for (int i = 0; i < 8; ++i)
#pragma unroll
    for (int j = 0; j < 4; ++j) acc[i][j] = f32x4{0.f, 0.f, 0.f, 0.f};

  // prologue: tile 0 fully + B halves of tile 1 (A halves of tile 1 staged in tile 0's ph0/ph1)
  stA(0, 0, 0); stA(0, 1, 0); stB(0, 0, 0); stB(0, 1, 0);
  stB(1, 0, 1); stB(1, 1, 1);
  asm volatile("s_waitcnt vmcnt(4)" ::: "memory");  // tile 0's 4 halves landed
  SBAR_; HBAR_;

  for (int t = 0; t < nt; ++t) {
    const int buf = t & 1;
    // ---- ph0: read A(m0)+B(n0); stage A0(t+1); MFMA waits per-operand (counted) ----
    SBAR_;
    RD_A(buf, 0); RD_B(buf, 0);
    if (t + 1 < nt) stA(t + 1, 0, buf ^ 1);
    SBAR_; HBAR_;
    MFMA_Q(0, 0);
    SBAR_; HBAR_;
    // ---- ph1: read B(n1); stage A1(t+1) ----
    SBAR_;
    RD_B(buf, 1);
    if (t + 1 < nt) stA(t + 1, 1, buf ^ 1);
    SBAR_; HBAR_;
    MFMA_Q(0, 1);
    SBAR_; HBAR_;
    // ---- ph2: read A(m1); stage B0(t+2) over consumed B0 ----
    SBAR_;
    RD_A(buf, 1);
    if (t + 2 < nt) stB(t + 2, 0, buf);
    SBAR_; HBAR_;
    MFMA_Q(1, 1);
    SBAR_; HBAR_;
    // ---- ph3: no reads (B(n0) held in regs); stage B1(t+2); counted vmcnt ----
    SBAR_;
    if (t + 2 < nt) {
      stB(t + 2, 1, buf);
      asm volatile("s_waitcnt vmcnt(4)" ::: "memory");  // all of tile t+1 landed
    } else {
      asm volatile("s_waitcnt vmcnt(0)" ::: "memory");  // drain tail
    }
    SBAR_; HBAR_; SBAR_;
    MFMA_Q(1, 0);
    SBAR_; HBAR_;
  }

  // epilogue: 16x16x32 C-layout col=lane&15, row=(lane>>4)*4+r
#pragma unroll
  for (int mfg = 0; mfg < 8; ++mfg)
#pragma unroll
    for (int nfg = 0; nfg < 4; ++nfg) {
      const int col = col0 + wn * 64 + (nfg >> 1) * 32 + (nfg & 1) * 16 + fr;
#pragma unroll
      for (int r = 0; r < 4; ++r) {
        const int row = row0 + wm * 128 + mfg * 16 + fq * 4 + r;
        C[(size_t)row * N + col] = (CT)acc[mfg][nfg][r];
      }
    }
}

// ---------------- fused in-place RoPE for q_comb and kv_comb rope slices (1 launch) ----------------
#define QROPE_BLOCKS ((B_ * LQ * H_) / 8)
__global__ __launch_bounds__(256) void rope2_kernel(bf16_t* __restrict__ qbase, bf16_t* __restrict__ kvbase) {
  const int bid = blockIdx.x;
  bf16_t* base;
  int tokStride, hshift, posMask;
  long bidl;
  if (bid < QROPE_BLOCKS) { base = qbase; tokStride = QCOMB; hshift = 4; posMask = LQ - 1; bidl = bid; }
  else { base = kvbase; tokStride = KCOMB; hshift = 0; posMask = LK - 1; bidl = bid - QROPE_BLOCKS; }
  const long idx = bidl * 8 + (threadIdx.x >> 5);  // tok*heads + h
  const int i = threadIdx.x & 31;
  const long tok = idx >> hshift;
  const int h = (int)(idx & ((1 << hshift) - 1));
  const int pos = (int)(tok & posMask);
  bf16_t* p = base + tok * (long)tokStride + h * 64;
  const float x1 = (float)p[i], x2 = (float)p[i + 32];
  const float invf = expf(-((float)i * (1.0f / 32.f)) * 9.210340371976184f);  // ln(10000)
  float sn, cs;
  sincosf((float)pos * invf, &sn, &cs);
  p[i]      = (bf16_t)(x1 * cs - x2 * sn);
  p[i + 32] = (bf16_t)(x1 * sn + x2 * cs);
}

// ---------------- sparse windowed attention: <=9 keys per query ----------------
__global__ __launch_bounds__(256) void attn_sparse(
    const bf16_t* __restrict__ qc, const bf16_t* __restrict__ kvc,
    const int* __restrict__ seg, bf16_t* __restrict__ out) {
  const int qrow = blockIdx.x * 4 + (threadIdx.x >> 6);  // b*LQ + qi
  const int lane = threadIdx.x & 63;
  const int h = lane >> 2, sub = lane & 3;
  const int b = qrow >> 12;  // / LQ
  const int s = seg[qrow];
  const int kl = max(0, s - 8);
  const float scale = 0.07216878364870322f;  // 1/sqrt(HD+R)

  float qnf[32], qrf[16];
  {
    const bf16_t* p = qc + (size_t)qrow * QCOMB + h * HD_ + sub * 32;
#pragma unroll
    for (int j = 0; j < 4; ++j) {
      bf16x8 t = *(const bf16x8*)(p + j * 8);
#pragma unroll
      for (int e = 0; e < 8; ++e) qnf[j * 8 + e] = (float)t[e];
    }
    const bf16_t* p2 = qc + (size_t)qrow * QCOMB + 2048 + h * R_ + sub * 16;
#pragma unroll
    for (int j = 0; j < 2; ++j) {
      bf16x8 t = *(const bf16x8*)(p2 + j * 8);
#pragma unroll
      for (int e = 0; e < 8; ++e) qrf[j * 8 + e] = (float)t[e];
    }
  }

  float sc[9];
#pragma unroll
  for (int kk = 0; kk < 9; ++kk) {
    const int kx = kl + kk;
    const bf16_t* kb = kvc + (size_t)(b * LK + kx) * KCOMB;
    float d = 0.f;
    const bf16_t* p = kb + h * HD_ + sub * 32;
#pragma unroll
    for (int j = 0; j < 4; ++j) {
      bf16x8 t = *(const bf16x8*)(p + j * 8);
#pragma unroll
      for (int e = 0; e < 8; ++e) d += qnf[j * 8 + e] * (float)t[e];
    }
    const bf16_t* p2 = kb + 4096 + sub * 16;
#pragma unroll
    for (int j = 0; j < 2; ++j) {
      bf16x8 t = *(const bf16x8*)(p2 + j * 8);
#pragma unroll
      for (int e = 0; e < 8; ++e) d += qrf[j * 8 + e] * (float)t[e];
    }
    d += __shfl_xor(d, 1);
    d += __shfl_xor(d, 2);
    sc[kk] = (kx <= s) ? d * scale : -1e30f;
  }
  float m = sc[0];
#pragma unroll
  for (int kk = 1; kk < 9; ++kk) m = fmaxf(m, sc[kk]);
  float sum = 0.f;
#pragma unroll
  for (int kk = 0; kk < 9; ++kk) { const float p = expf(sc[kk] - m); sc[kk] = p; sum += p; }
  const float inv = 1.f / sum;

  float o[32];
#pragma unroll
  for (int j = 0; j < 32; ++j) o[j] = 0.f;
#pragma unroll
  for (int kk = 0; kk < 9; ++kk) {
    const bf16_t* pv = kvc + (size_t)(b * LK + kl + kk) * KCOMB + 2048 + h * HD_ + sub * 32;
    const float p = sc[kk] * inv;
#pragma unroll
    for (int j = 0; j < 4; ++j) {
      bf16x8 t = *(const bf16x8*)(pv + j * 8);
#pragma unroll
      for (int e = 0; e < 8; ++e) o[j * 8 + e] += p * (float)t[e];
    }
  }
  bf16_t* po = out + (size_t)qrow * (H_ * HD_) + h * HD_ + sub * 32;
#pragma unroll
  for (int j = 0; j < 4; ++j) {
    bf16x8 t;
#pragma unroll
    for (int e = 0; e < 8; ++e) t[e] = (bf16_t)o[j * 8 + e];
    *(bf16x8*)(po + j * 8) = t;
  }
}

extern "C" void kernel_launch(void* const* d_in, const int* in_sizes, int n_in,
                              void* d_out, int out_size, void* d_ws, size_t ws_size,
                              hipStream_t stream) {
  const float* q     = (const float*)d_in[0];
  const float* kv    = (const float*)d_in[1];
  const int*   seg   = (const int*)d_in[2];
  const float* W_kvc = (const float*)d_in[3];
  const float* W_dq  = (const float*)d_in[4];
  const float* W_uq  = (const float*)d_in[5];
  const float* W_qr  = (const float*)d_in[6];
  const float* W_uk  = (const float*)d_in[7];
  const float* W_kr  = (const float*)d_in[8];
  const float* W_uv  = (const float*)d_in[9];
  const float* W_o   = (const float*)d_in[10];
  float* out = (float*)d_out;
  (void)in_sizes; (void)n_in; (void)out_size; (void)ws_size;

  char* ws = (char*)d_ws;
  size_t off = 0;
  auto alloc = [&](size_t bytes) {
    char* p = ws + off;
    off = (off + bytes + 255) & ~(size_t)255;
    return p;
  };
  bf16_t* q_bf    = (bf16_t*)alloc((size_t)B_ * LQ * QDIM * 2);   // reused as attn_o
  bf16_t* kv_bf   = (bf16_t*)alloc((size_t)B_ * LK * KVDIM * 2);
  bf16_t* WkvcT   = (bf16_t*)alloc((size_t)KVC_ * KVDIM * 2);
  bf16_t* WdqT    = (bf16_t*)alloc((size_t)QC_ * QDIM * 2);
  bf16_t* WuqrT   = (bf16_t*)alloc((size_t)QCOMB * QC_ * 2);      // [W_uq^T ; W_qr^T]
  bf16_t* WkvT    = (bf16_t*)alloc((size_t)KCOMB * KVC_ * 2);     // [W_uk^T ; W_uv^T ; W_kr^T ; pad]
  bf16_t* WoT     = (bf16_t*)alloc((size_t)QDIM * (H_ * HD_) * 2);
  bf16_t* kv_c    = (bf16_t*)alloc((size_t)B_ * LK * KVC_ * 2);
  bf16_t* q_c     = (bf16_t*)alloc((size_t)B_ * LQ * QC_ * 2);
  bf16_t* q_comb  = (bf16_t*)alloc((size_t)B_ * LQ * QCOMB * 2);
  bf16_t* kv_comb = (bf16_t*)alloc((size_t)B_ * LK * KCOMB * 2);
  bf16_t* attn_o  = q_bf;  // q_bf dead after q_c GEMM

  // ---- convert inputs to bf16 (1 launch) ----
  cvt2_f32_bf16<<<4096, 256, 0, stream>>>(q, q_bf, (long)B_ * LQ * QDIM,
                                          kv, kv_bf, (long)B_ * LK * KVDIM);

  // ---- transpose+convert ALL weights (1 launch) ----
  {
    TransAll d;
    auto set = [&](int i, const float* s, bf16_t* dt, int K, int N) {
      d.src[i] = s; d.dst[i] = dt; d.K[i] = K; d.N[i] = N; d.gx[i] = N / 32;
    };
    set(0, W_kvc, WkvcT, KVDIM, KVC_);
    set(1, W_dq,  WdqT,  QDIM,  QC_);
    set(2, W_uq,  WuqrT, QC_,   H_ * HD_);
    set(3, W_qr,  WuqrT + (size_t)(H_ * HD_) * QC_, QC_, H_ * R_);
    set(4, W_uk,  WkvT,  KVC_,  H_ * HD_);
    set(5, W_uv,  WkvT + (size_t)(H_ * HD_) * KVC_, KVC_, H_ * HD_);
    set(6, W_kr,  WkvT + (size_t)2 * (H_ * HD_) * KVC_, KVC_, R_);
    set(7, W_o,   WoT,   H_ * HD_, QDIM);
    int acc_off = 0;
    for (int i = 0; i < 8; ++i) {
      d.off[i] = acc_off;
      acc_off += (d.N[i] / 32) * (d.K[i] / 32);
    }
    d.off[8] = acc_off;
    transpose_all<<<acc_off, dim3(32, 8), 0, stream>>>(d);
  }

  // ---- fused kv_c + q_dq GEMM (independent; one launch fills the machine) ----
  gemm_dual<<<224, 512, 0, stream>>>(
      kv_bf, WkvcT, kv_c, KVC_, KVDIM,
      q_bf, WdqT, q_c, QC_, QDIM, 32);

  // ---- up-projections ----
  gemm_8ph<bf16_t><<<dim3(QCOMB / 256, (B_ * LQ) / 256), 512, 0, stream>>>(
      q_c, WuqrT, q_comb, B_ * LQ, QCOMB, QC_);
  gemm_big2<128, bf16_t><<<dim3(KCOMB / 128, (B_ * LK) / 256), 512, 0, stream>>>(
      kv_c, WkvT, kv_comb, B_ * LK, KCOMB, KVC_);

  // ---- fused RoPE (q + kv slices, 1 launch) ----
  rope2_kernel<<<QROPE_BLOCKS + (B_ * LK) / 8, 256, 0, stream>>>(q_comb + 2048, kv_comb + 4096);

  // ---- sparse attention (<=9 keys/query) ----
  attn_sparse<<<(B_ * LQ) / 4, 256, 0, stream>>>(q_comb, kv_comb, seg, attn_o);

  // ---- output projection ----
  gemm_8ph<float><<<dim3(QDIM / 256, (B_ * LQ) / 256), 512, 0, stream>>>(
      attn_o, WoT, out, B_ * LQ, QDIM, H_ * HD_);
}